// Round 5
// baseline (141.329 us; speedup 1.0000x reference)
//
#include <hip/hip_runtime.h>

// CompositeLoss R16: d-pair threads (2 adjacent d-planes, straight-line).
// R15 post-mortem: pinned loads gained only 11% (45->~40us) because the
// kernel is ALSO instruction-issue bound: ~700 issue-slots/wave (math +
// 13-acc shuffle-reduce epilogue) ~ 1400cy/wave * 64 waves/CU ~ the whole
// measured 96Kcy budget. R16 attacks both: each thread owns planes d0,d0+1
// so plane0's d-neighbor comes from plane1's REGISTERS (35 f4 loads per 2
// groups vs 42), and the reduce/mask/store overhead amortizes over 2
// groups. Straight-line, branch-free, every pinned value consumed once --
// NOT R12's loop-carried shape (that spill came from a 4-iter loop + tail).
// __launch_bounds__(256,2): 256-VGPR budget, 140 pinned f4 dests fit, no
// spill by construction. d-pairs: (2dp,2dp+1) always + (2dp+1,2dp+2)*dv
// = exactly the 127 reference pairs. Tripwire: WRITE_SIZE ~0.5MB.
// Partial rows: 4 waves/block * 2048 blocks = 8192 rows of 16.
//  0:M 1:Mx(d) 2:My(h) 3:Mz(w)  4:Smae 5:Smse 6:Sbg
//  7:Sgx 8:Sgy 9:Sgz  10:Stx 11:Sty 12:Stz
#define NACC 13
#define NPAD 16
#define NBLOCKS 2048   // 2^19 threads; thread = (b, dp, h, w4), 2 planes
#define NROWS 8192     // NBLOCKS * 4 waves
#define NMID 32        // 8192 / 256

__device__ __forceinline__ float4 ld4(const float* p) {
    return *reinterpret_cast<const float4*>(p);
}

__global__ __launch_bounds__(256, 2) void loss_main(
    const float* __restrict__ pred, const float* __restrict__ target,
    const float* __restrict__ mask, float* __restrict__ partials)
{
    float acc[NACC];
#pragma unroll
    for (int k = 0; k < NACC; ++k) acc[k] = 0.f;

    // g = (b, dp, h, w4); w4 in lane bits so the w-shfl trick still works.
    const int g  = blockIdx.x * 256 + threadIdx.x;
    const int w4 = g & 31;
    const int h  = (g >> 5) & 127;
    const int dp = (g >> 12) & 63;   // block-uniform (bits >= 8)
    const int b  = g >> 18;          // block-uniform
    const int w  = w4 << 2;
    const int d0 = dp << 1;

    const float wv = (w4 < 31) ? 1.f : 0.f;
    const float hv = (h < 127) ? 1.f : 0.f;
    const float dv = (dp < 63) ? 1.f : 0.f;
    const int oh  = (h < 127) ? 128 : 0;
    const int od2 = (dp < 63) ? 32768 : 0;   // +2 planes, clamped

    const int mb  = b * 2097152 + d0 * 16384 + h * 128 + w;
    const int pb0 = b * 6291456 + d0 * 16384 + h * 128 + w;

    // ---- 35 pinned float4 loads, issue order == consumption order ----
    const float4 a0  = ld4(mask + mb);            // plane d0
    const float4 a1  = ld4(mask + mb + 16384);    // plane d0+1
    const float4 a2  = ld4(mask + mb + od2);      // plane d0+2 (clamped)
    const float4 ah0 = ld4(mask + mb + oh);
    const float4 ah1 = ld4(mask + mb + 16384 + oh);
    float4 P0[3], T0[3], P1[3], T1[3], PH0[3], TH0[3],
           PH1[3], TH1[3], P2[3], T2[3];
#pragma unroll
    for (int c = 0; c < 3; ++c) {
        const int pb = pb0 + c * 2097152;
        P0[c]  = ld4(pred + pb);             T0[c]  = ld4(target + pb);
        P1[c]  = ld4(pred + pb + 16384);     T1[c]  = ld4(target + pb + 16384);
        PH0[c] = ld4(pred + pb + oh);        TH0[c] = ld4(target + pb + oh);
        PH1[c] = ld4(pred + pb + 16384+oh);  TH1[c] = ld4(target + pb + 16384+oh);
        P2[c]  = ld4(pred + pb + od2);       T2[c]  = ld4(target + pb + od2);
    }
    __builtin_amdgcn_sched_barrier(0);   // loads may not sink past here

    const float m4w0 = __shfl_down(a0.x, 1, 64);  // lane w4=31: wv=0 kills
    const float m4w1 = __shfl_down(a1.x, 1, 64);

    // W pairs (within each plane)
    const float z00=fminf(a0.x,a0.y), z01=fminf(a0.y,a0.z),
                z02=fminf(a0.z,a0.w), z03=fminf(a0.w,m4w0)*wv;
    const float z10=fminf(a1.x,a1.y), z11=fminf(a1.y,a1.z),
                z12=fminf(a1.z,a1.w), z13=fminf(a1.w,m4w1)*wv;
    // H pairs
    const float y00=fminf(a0.x,ah0.x)*hv, y01=fminf(a0.y,ah0.y)*hv,
                y02=fminf(a0.z,ah0.z)*hv, y03=fminf(a0.w,ah0.w)*hv;
    const float y10=fminf(a1.x,ah1.x)*hv, y11=fminf(a1.y,ah1.y)*hv,
                y12=fminf(a1.z,ah1.z)*hv, y13=fminf(a1.w,ah1.w)*hv;
    // D pairs: (d0,d0+1) always interior; (d0+1,d0+2) gated by dv
    const float x00=fminf(a0.x,a1.x), x01=fminf(a0.y,a1.y),
                x02=fminf(a0.z,a1.z), x03=fminf(a0.w,a1.w);
    const float x10=fminf(a1.x,a2.x)*dv, x11=fminf(a1.y,a2.y)*dv,
                x12=fminf(a1.z,a2.z)*dv, x13=fminf(a1.w,a2.w)*dv;

    acc[0] = a0.x+a0.y+a0.z+a0.w + a1.x+a1.y+a1.z+a1.w;
    acc[1] = x00+x01+x02+x03 + x10+x11+x12+x13;
    acc[2] = y00+y01+y02+y03 + y10+y11+y12+y13;
    acc[3] = z00+z01+z02+z03 + z10+z11+z12+z13;

#pragma unroll
    for (int c = 0; c < 3; ++c) {
        const float4 p0 = P0[c],  t0 = T0[c];
        const float4 p1 = P1[c],  t1 = T1[c];
        const float4 h0 = PH0[c], g0 = TH0[c];
        const float4 h1 = PH1[c], g1 = TH1[c];
        const float4 p2 = P2[c],  t2 = T2[c];
        const float p4_0 = __shfl_down(p0.x, 1, 64);
        const float t4_0 = __shfl_down(t0.x, 1, 64);
        const float p4_1 = __shfl_down(p1.x, 1, 64);
        const float t4_1 = __shfl_down(t1.x, 1, 64);

        // plane-0 / plane-1 errors
        const float e0x=p0.x-t0.x, e0y=p0.y-t0.y, e0z=p0.z-t0.z, e0w=p0.w-t0.w;
        const float e1x=p1.x-t1.x, e1y=p1.y-t1.y, e1z=p1.z-t1.z, e1w=p1.w-t1.w;
        const float e4_0 = p4_0 - t4_0, e4_1 = p4_1 - t4_1;
        // plane-2 errors (garbage when dv=0; all uses gated by x1*)
        const float e2x=p2.x-t2.x, e2y=p2.y-t2.y, e2z=p2.z-t2.z, e2w=p2.w-t2.w;

        // MAE / MSE / BG, both planes
        acc[4] += fabsf(e0x)*a0.x + fabsf(e0y)*a0.y
                + fabsf(e0z)*a0.z + fabsf(e0w)*a0.w
                + fabsf(e1x)*a1.x + fabsf(e1y)*a1.y
                + fabsf(e1z)*a1.z + fabsf(e1w)*a1.w;
        acc[5] += e0x*e0x*a0.x + e0y*e0y*a0.y + e0z*e0z*a0.z + e0w*e0w*a0.w
                + e1x*e1x*a1.x + e1y*e1y*a1.y + e1z*e1z*a1.z + e1w*e1w*a1.w;
        acc[6] += fabsf(p0.x)*(1.f-a0.x) + fabsf(p0.y)*(1.f-a0.y)
                + fabsf(p0.z)*(1.f-a0.z) + fabsf(p0.w)*(1.f-a0.w)
                + fabsf(p1.x)*(1.f-a1.x) + fabsf(p1.y)*(1.f-a1.y)
                + fabsf(p1.z)*(1.f-a1.z) + fabsf(p1.w)*(1.f-a1.w);

        // W direction (reference dz)
        acc[9]  += fabsf(e0y-e0x)*z00 + fabsf(e0z-e0y)*z01
                 + fabsf(e0w-e0z)*z02 + fabsf(e4_0-e0w)*z03
                 + fabsf(e1y-e1x)*z10 + fabsf(e1z-e1y)*z11
                 + fabsf(e1w-e1z)*z12 + fabsf(e4_1-e1w)*z13;
        acc[12] += fabsf(p0.y-p0.x)*z00 + fabsf(p0.z-p0.y)*z01
                 + fabsf(p0.w-p0.z)*z02 + fabsf(p4_0-p0.w)*z03
                 + fabsf(p1.y-p1.x)*z10 + fabsf(p1.z-p1.y)*z11
                 + fabsf(p1.w-p1.z)*z12 + fabsf(p4_1-p1.w)*z13;

        // H direction (reference dy)
        acc[8]  += fabsf((h0.x-g0.x)-e0x)*y00 + fabsf((h0.y-g0.y)-e0y)*y01
                 + fabsf((h0.z-g0.z)-e0z)*y02 + fabsf((h0.w-g0.w)-e0w)*y03
                 + fabsf((h1.x-g1.x)-e1x)*y10 + fabsf((h1.y-g1.y)-e1y)*y11
                 + fabsf((h1.z-g1.z)-e1z)*y12 + fabsf((h1.w-g1.w)-e1w)*y13;
        acc[11] += fabsf(h0.x-p0.x)*y00 + fabsf(h0.y-p0.y)*y01
                 + fabsf(h0.z-p0.z)*y02 + fabsf(h0.w-p0.w)*y03
                 + fabsf(h1.x-p1.x)*y10 + fabsf(h1.y-p1.y)*y11
                 + fabsf(h1.z-p1.z)*y12 + fabsf(h1.w-p1.w)*y13;

        // D direction (reference dx): pair (d0,d0+1) from registers,
        // pair (d0+1,d0+2) from the p2/t2 loads (gated by x1*)
        acc[7]  += fabsf(e1x-e0x)*x00 + fabsf(e1y-e0y)*x01
                 + fabsf(e1z-e0z)*x02 + fabsf(e1w-e0w)*x03
                 + fabsf(e2x-e1x)*x10 + fabsf(e2y-e1y)*x11
                 + fabsf(e2z-e1z)*x12 + fabsf(e2w-e1w)*x13;
        acc[10] += fabsf(p1.x-p0.x)*x00 + fabsf(p1.y-p0.y)*x01
                 + fabsf(p1.z-p0.z)*x02 + fabsf(p1.w-p0.w)*x03
                 + fabsf(p2.x-p1.x)*x10 + fabsf(p2.y-p1.y)*x11
                 + fabsf(p2.z-p1.z)*x12 + fabsf(p2.w-p1.w)*x13;
    }

    // per-wave shuffle reduce -> own partials row; NO __syncthreads.
    const int lane = threadIdx.x & 63;
    const int wave = threadIdx.x >> 6;
    float mine = 0.f;   // lane k (<16) ends up holding total of acc[k]
#pragma unroll
    for (int k = 0; k < NACC; ++k) {
        float v = acc[k];
        for (int o = 32; o > 0; o >>= 1) v += __shfl_down(v, o, 64);
        const float tot = __shfl(v, 0, 64);
        if (lane == k) mine = tot;
    }
    if (lane < NPAD)
        partials[(blockIdx.x * 4 + wave) * NPAD + lane] = mine; // pad rows=0
}

// Level 1: 32 blocks x 256 threads; thread r reads row r (4 independent
// float4), block-reduces 256 rows -> 1 row. 32 CUs share the 512 KiB read.
__global__ __launch_bounds__(256) void loss_mid(
    const float* __restrict__ partials, float* __restrict__ mid)
{
    const int r = blockIdx.x * 256 + threadIdx.x;   // exactly covers 8192
    const float* row = partials + r * NPAD;
    const float4 r0 = ld4(row);     const float4 r1 = ld4(row + 4);
    const float4 r2 = ld4(row + 8); const float4 r3 = ld4(row + 12);
    float acc[NPAD] = {r0.x, r0.y, r0.z, r0.w, r1.x, r1.y, r1.z, r1.w,
                       r2.x, r2.y, r2.z, r2.w, r3.x, r3.y, r3.z, r3.w};

    const int lane = threadIdx.x & 63;
    const int wave = threadIdx.x >> 6;
    __shared__ float red[4][NPAD];
#pragma unroll
    for (int k = 0; k < NPAD; ++k) {
        float v = acc[k];
        for (int o = 32; o > 0; o >>= 1) v += __shfl_down(v, o, 64);
        if (lane == 0) red[wave][k] = v;
    }
    __syncthreads();
    if (threadIdx.x < NPAD) {
        const int k = threadIdx.x;
        mid[blockIdx.x * NPAD + k] =
            red[0][k] + red[1][k] + red[2][k] + red[3][k];
    }
}

// Level 2: one wave; lane l (<32) reads mid row l, shuffle-reduce,
// lane 0 does the scalar epilogue.
__global__ __launch_bounds__(64) void loss_final(
    const float* __restrict__ mid, float* __restrict__ out)
{
    const int lane = threadIdx.x;
    float acc[NPAD];
    if (lane < NMID) {
        const float* row = mid + lane * NPAD;
        const float4 r0 = ld4(row);     const float4 r1 = ld4(row + 4);
        const float4 r2 = ld4(row + 8); const float4 r3 = ld4(row + 12);
        acc[0] = r0.x;  acc[1] = r0.y;  acc[2] = r0.z;  acc[3] = r0.w;
        acc[4] = r1.x;  acc[5] = r1.y;  acc[6] = r1.z;  acc[7] = r1.w;
        acc[8] = r2.x;  acc[9] = r2.y;  acc[10] = r2.z; acc[11] = r2.w;
        acc[12] = r3.x; acc[13] = r3.y; acc[14] = r3.z; acc[15] = r3.w;
    } else {
#pragma unroll
        for (int k = 0; k < NPAD; ++k) acc[k] = 0.f;
    }
#pragma unroll
    for (int k = 0; k < NACC; ++k) {
        for (int o = 32; o > 0; o >>= 1) acc[k] += __shfl_down(acc[k], o, 64);
    }
    if (lane == 0) {
        const float EPS = 1e-8f;
        const float M = acc[0], Mx = acc[1], My = acc[2], Mz = acc[3];
        float loss = (acc[4] + acc[5]) / (3.f * M + EPS);   // W_MAE=1, W_MSE=1
        loss += 0.1f   * (acc[7] / (3.f*Mx + EPS) + acc[8] / (3.f*My + EPS)
                        + acc[9] / (3.f*Mz + EPS));
        loss += 0.002f * (acc[10] / (3.f*Mx + EPS) + acc[11] / (3.f*My + EPS)
                        + acc[12] / (3.f*Mz + EPS));
        const float inv = 4194304.f - M;  // B*D*H*W - M
        loss += 0.15f * acc[6] / (3.f * inv + EPS);
        out[0] = loss;
    }
}

extern "C" void kernel_launch(void* const* d_in, const int* in_sizes, int n_in,
                              void* d_out, int out_size, void* d_ws, size_t ws_size,
                              hipStream_t stream) {
    const float* pred   = (const float*)d_in[0];
    const float* target = (const float*)d_in[1];
    const float* mask   = (const float*)d_in[2];
    float* out      = (float*)d_out;
    float* partials = (float*)d_ws;                 // 8192*16 floats = 512 KiB
    float* mid      = partials + NROWS * NPAD;      // 32*16 floats

    loss_main<<<NBLOCKS, 256, 0, stream>>>(pred, target, mask, partials);
    loss_mid<<<NMID, 256, 0, stream>>>(partials, mid);
    loss_final<<<1, 64, 0, stream>>>(mid, out);
}